// Round 1
// baseline (359.461 us; speedup 1.0000x reference)
//
#include <hip/hip_runtime.h>
#include <hip/hip_bf16.h>

typedef __bf16 bf16x8 __attribute__((ext_vector_type(8)));
typedef float f32x4 __attribute__((ext_vector_type(4)));
typedef __hip_bfloat16 bf16;

#define NEG_INF_F (-4294967295.0f)
#define QK_SCALE 0.125f

__device__ __forceinline__ f32x4 mfma_bf16(bf16x8 a, bf16x8 b, f32x4 c) {
  return __builtin_amdgcn_mfma_f32_16x16x32_bf16(a, b, c, 0, 0, 0);
}

__device__ __forceinline__ void gload16(const void* g, void* l) {
  __builtin_amdgcn_global_load_lds(
      (const __attribute__((address_space(1))) void*)g,
      (__attribute__((address_space(3))) void*)l, 16, 0, 0);
}

// ---------------- prep: fp32 -> bf16 convert ----------------
__global__ void cvt_bf16_kernel(const float* __restrict__ in, bf16* __restrict__ out) {
  int i = (blockIdx.x * 256 + threadIdx.x) * 4;
  float4 v = *reinterpret_cast<const float4*>(in + i);
  union { bf16 h[4]; uint2 u; } t;
  t.h[0] = __float2bfloat16(v.x);
  t.h[1] = __float2bfloat16(v.y);
  t.h[2] = __float2bfloat16(v.z);
  t.h[3] = __float2bfloat16(v.w);
  *reinterpret_cast<uint2*>(out + i) = t.u;
}

// ---------------- prep: transpose weights to (N,K) bf16 ----------------
__global__ void transpose_w_kernel(const float* __restrict__ Wq, const float* __restrict__ Wk,
                                   const float* __restrict__ Wv, const float* __restrict__ Wo,
                                   bf16* __restrict__ Wqkv_t, bf16* __restrict__ Wot) {
  __shared__ float tile[32][33];
  int z = blockIdx.z;
  const float* src = (z == 0) ? Wq : (z == 1) ? Wk : (z == 2) ? Wv : Wo;
  bf16* dst = (z < 3) ? (Wqkv_t + (size_t)z * 1048576) : Wot;
  int tx = threadIdx.x, ty = threadIdx.y;
  int c0 = blockIdx.x * 32, r0 = blockIdx.y * 32;
#pragma unroll
  for (int i = 0; i < 32; i += 8)
    tile[ty + i][tx] = src[(r0 + ty + i) * 1024 + c0 + tx];
  __syncthreads();
#pragma unroll
  for (int i = 0; i < 32; i += 8)
    dst[(c0 + ty + i) * 1024 + r0 + tx] = __float2bfloat16(tile[tx][ty + i]);
}

// ---------------- fused QKV GEMM: C = X(8192x1024) @ Wqkv^T, scatter to heads ----------------
// m97 structure: 128x128 tile, BK=32, 4 waves (2x2), 16x16x32 MFMA, global_load_lds w=16.
__global__ __launch_bounds__(256) void gemm_qkv_kernel(
    const bf16* __restrict__ A, const bf16* __restrict__ Bt,
    const float* __restrict__ bq, const float* __restrict__ bk, const float* __restrict__ bv,
    bf16* __restrict__ Qb, bf16* __restrict__ Kb, bf16* __restrict__ Vt) {
  __shared__ __align__(16) bf16 As[128 * 32];
  __shared__ __align__(16) bf16 Bs[128 * 32];
  const int K = 1024;
  const int TILES_N = 24;
  int bid = blockIdx.x;
  int bm = bid / TILES_N, bn = bid % TILES_N;
  int t = threadIdx.x;
  int lane = t & 63, w = t >> 6;
  int fr = lane & 15, fk = (lane >> 4) * 8;
  int wr = w >> 1, wc = w & 1;
  int srow = t >> 2, scol = (t & 3) * 8;

  const bf16* Ablk = A + (size_t)(bm * 128) * K;
  const bf16* Bblk = Bt + (size_t)(bn * 128) * K;

  f32x4 acc[4][4] = {};

  for (int k0 = 0; k0 < K; k0 += 32) {
    gload16(Ablk + (size_t)srow * K + k0 + scol, (char*)As + t * 16);
    gload16(Ablk + (size_t)(srow + 64) * K + k0 + scol, (char*)As + 4096 + t * 16);
    gload16(Bblk + (size_t)srow * K + k0 + scol, (char*)Bs + t * 16);
    gload16(Bblk + (size_t)(srow + 64) * K + k0 + scol, (char*)Bs + 4096 + t * 16);
    __syncthreads();
    bf16x8 a[4], b[4];
#pragma unroll
    for (int m = 0; m < 4; m++) a[m] = *(const bf16x8*)&As[(wr * 64 + m * 16 + fr) * 32 + fk];
#pragma unroll
    for (int n = 0; n < 4; n++) b[n] = *(const bf16x8*)&Bs[(wc * 64 + n * 16 + fr) * 32 + fk];
#pragma unroll
    for (int m = 0; m < 4; m++)
#pragma unroll
      for (int n = 0; n < 4; n++)
        acc[m][n] = mfma_bf16(a[m], b[n], acc[m][n]);
    __syncthreads();
  }

  // epilogue: C row = (b,n_seq), col = sel*1024 + h*64 + d
  int sel = (bn * 128) >> 10;  // uniform per block (1024 % 128 == 0)
  const float* bias = (sel == 0) ? bq : (sel == 1) ? bk : bv;
#pragma unroll
  for (int m = 0; m < 4; m++) {
#pragma unroll
    for (int n = 0; n < 4; n++) {
      f32x4 c = acc[m][n];
#pragma unroll
      for (int j = 0; j < 4; j++) {
        int grow = bm * 128 + wr * 64 + m * 16 + (lane >> 4) * 4 + j;
        int gcol = bn * 128 + wc * 64 + n * 16 + fr;
        int cc = gcol & 1023;
        float val = c[j] + bias[cc];
        int bb = grow >> 10, nr = grow & 1023;
        int h = cc >> 6, d = cc & 63;
        int bh = bb * 16 + h;
        if (sel == 0) {
          Qb[((size_t)bh * 1024 + nr) * 64 + d] = __float2bfloat16(val * QK_SCALE);
        } else if (sel == 1) {
          Kb[((size_t)bh * 1024 + nr) * 64 + d] = __float2bfloat16(val);
        } else {
          Vt[((size_t)bh * 64 + d) * 1024 + nr] = __float2bfloat16(val);
        }
      }
    }
  }
}

// ---------------- flash attention ----------------
// grid: 2048 blocks; bid&127 = head (keeps one head's 16 blocks on one XCD), bid>>7 = q-tile.
// 4 waves/block, each wave owns 16 q rows, loops K/V in 32-key tiles, online softmax.
__global__ __launch_bounds__(256) void attn_kernel(
    const bf16* __restrict__ Qb, const bf16* __restrict__ Kb, const bf16* __restrict__ Vt,
    const int* __restrict__ mask, bf16* __restrict__ AO) {
  __shared__ int smask[1024];
  __shared__ __align__(16) bf16 pbuf[4][16][32];

  int bid = blockIdx.x;
  int qt = bid >> 7;
  int bh = bid & 127;
  int b = bh >> 4, h = bh & 15;
  int t = threadIdx.x, w = t >> 6, lane = t & 63;
  int fr = lane & 15, g = lane >> 4, fk = g * 8;

  for (int i = t; i < 1024; i += 256) smask[i] = mask[b * 1024 + i];
  __syncthreads();

  const bf16* Qh = Qb + (size_t)bh * 1024 * 64;
  const bf16* Kh = Kb + (size_t)bh * 1024 * 64;
  const bf16* Vh = Vt + (size_t)bh * 64 * 1024;

  int qbase = qt * 64 + w * 16;
  bf16x8 qa0 = *(const bf16x8*)&Qh[(qbase + fr) * 64 + fk];
  bf16x8 qa1 = *(const bf16x8*)&Qh[(qbase + fr) * 64 + 32 + fk];

  f32x4 acc[4] = {};
  f32x4 mrow, lrow;
#pragma unroll
  for (int j = 0; j < 4; j++) { mrow[j] = -3.0e38f; lrow[j] = 0.0f; }

  for (int kt = 0; kt < 1024; kt += 32) {
    f32x4 s0 = {}, s1 = {};
    bf16x8 k00 = *(const bf16x8*)&Kh[(kt + fr) * 64 + fk];
    bf16x8 k01 = *(const bf16x8*)&Kh[(kt + fr) * 64 + 32 + fk];
    bf16x8 k10 = *(const bf16x8*)&Kh[(kt + 16 + fr) * 64 + fk];
    bf16x8 k11 = *(const bf16x8*)&Kh[(kt + 16 + fr) * 64 + 32 + fk];
    s0 = mfma_bf16(qa0, k00, s0);
    s0 = mfma_bf16(qa1, k01, s0);
    s1 = mfma_bf16(qa0, k10, s1);
    s1 = mfma_bf16(qa1, k11, s1);

    // mask (replace, like reference)
    int msk0 = smask[kt + fr];
    int msk1 = smask[kt + 16 + fr];
#pragma unroll
    for (int j = 0; j < 4; j++) {
      if (msk0 == 0) s0[j] = NEG_INF_F;
      if (msk1 == 0) s1[j] = NEG_INF_F;
    }

    // online softmax: row stats live in the same lanes as acc rows
    f32x4 tm;
#pragma unroll
    for (int j = 0; j < 4; j++) {
      float v = fmaxf(s0[j], s1[j]);
      v = fmaxf(v, __shfl_xor(v, 1));
      v = fmaxf(v, __shfl_xor(v, 2));
      v = fmaxf(v, __shfl_xor(v, 4));
      v = fmaxf(v, __shfl_xor(v, 8));
      tm[j] = v;
    }
    f32x4 corr, rs;
#pragma unroll
    for (int j = 0; j < 4; j++) {
      float mnew = fmaxf(mrow[j], tm[j]);
      corr[j] = __expf(mrow[j] - mnew);
      s0[j] = __expf(s0[j] - mnew);
      s1[j] = __expf(s1[j] - mnew);
      float r = s0[j] + s1[j];
      r += __shfl_xor(r, 1);
      r += __shfl_xor(r, 2);
      r += __shfl_xor(r, 4);
      r += __shfl_xor(r, 8);
      rs[j] = r;
      mrow[j] = mnew;
    }
#pragma unroll
    for (int j = 0; j < 4; j++) lrow[j] = lrow[j] * corr[j] + rs[j];
#pragma unroll
    for (int nt = 0; nt < 4; nt++)
#pragma unroll
      for (int j = 0; j < 4; j++) acc[nt][j] *= corr[j];

    // P -> LDS (C-layout) -> A-fragment layout
#pragma unroll
    for (int j = 0; j < 4; j++) {
      pbuf[w][g * 4 + j][fr] = __float2bfloat16(s0[j]);
      pbuf[w][g * 4 + j][16 + fr] = __float2bfloat16(s1[j]);
    }
    bf16x8 pa = *(const bf16x8*)&pbuf[w][fr][fk];
#pragma unroll
    for (int nt = 0; nt < 4; nt++) {
      bf16x8 vf = *(const bf16x8*)&Vh[(nt * 16 + fr) * 1024 + kt + fk];
      acc[nt] = mfma_bf16(pa, vf, acc[nt]);
    }
  }

  // epilogue: O = acc / l, write (B,N,H*D) bf16
#pragma unroll
  for (int nt = 0; nt < 4; nt++) {
#pragma unroll
    for (int j = 0; j < 4; j++) {
      int qrow = qbase + g * 4 + j;
      float val = acc[nt][j] / lrow[j];
      AO[((size_t)(b * 1024 + qrow)) * 1024 + h * 64 + nt * 16 + fr] = __float2bfloat16(val);
    }
  }
}

// ---------------- output projection GEMM -> fp32 out ----------------
__global__ __launch_bounds__(256) void gemm_out_kernel(
    const bf16* __restrict__ A, const bf16* __restrict__ Bt,
    const float* __restrict__ bo, float* __restrict__ Out) {
  __shared__ __align__(16) bf16 As[128 * 32];
  __shared__ __align__(16) bf16 Bs[128 * 32];
  const int K = 1024;
  const int TILES_N = 8;
  int bid = blockIdx.x;
  int bm = bid / TILES_N, bn = bid % TILES_N;
  int t = threadIdx.x;
  int lane = t & 63, w = t >> 6;
  int fr = lane & 15, fk = (lane >> 4) * 8;
  int wr = w >> 1, wc = w & 1;
  int srow = t >> 2, scol = (t & 3) * 8;

  const bf16* Ablk = A + (size_t)(bm * 128) * K;
  const bf16* Bblk = Bt + (size_t)(bn * 128) * K;

  f32x4 acc[4][4] = {};

  for (int k0 = 0; k0 < K; k0 += 32) {
    gload16(Ablk + (size_t)srow * K + k0 + scol, (char*)As + t * 16);
    gload16(Ablk + (size_t)(srow + 64) * K + k0 + scol, (char*)As + 4096 + t * 16);
    gload16(Bblk + (size_t)srow * K + k0 + scol, (char*)Bs + t * 16);
    gload16(Bblk + (size_t)(srow + 64) * K + k0 + scol, (char*)Bs + 4096 + t * 16);
    __syncthreads();
    bf16x8 a[4], b[4];
#pragma unroll
    for (int m = 0; m < 4; m++) a[m] = *(const bf16x8*)&As[(wr * 64 + m * 16 + fr) * 32 + fk];
#pragma unroll
    for (int n = 0; n < 4; n++) b[n] = *(const bf16x8*)&Bs[(wc * 64 + n * 16 + fr) * 32 + fk];
#pragma unroll
    for (int m = 0; m < 4; m++)
#pragma unroll
      for (int n = 0; n < 4; n++)
        acc[m][n] = mfma_bf16(a[m], b[n], acc[m][n]);
    __syncthreads();
  }

#pragma unroll
  for (int m = 0; m < 4; m++) {
#pragma unroll
    for (int n = 0; n < 4; n++) {
      f32x4 c = acc[m][n];
#pragma unroll
      for (int j = 0; j < 4; j++) {
        int grow = bm * 128 + wr * 64 + m * 16 + (lane >> 4) * 4 + j;
        int gcol = bn * 128 + wc * 64 + n * 16 + fr;
        Out[(size_t)grow * 1024 + gcol] = c[j] + bo[gcol];
      }
    }
  }
}

extern "C" void kernel_launch(void* const* d_in, const int* in_sizes, int n_in,
                              void* d_out, int out_size, void* d_ws, size_t ws_size,
                              hipStream_t stream) {
  const float* X = (const float*)d_in[0];
  const int* mask = (const int*)d_in[1];
  const float* Wq = (const float*)d_in[2];
  const float* bq = (const float*)d_in[3];
  const float* Wk = (const float*)d_in[4];
  const float* bk = (const float*)d_in[5];
  const float* Wv = (const float*)d_in[6];
  const float* bv = (const float*)d_in[7];
  const float* Wo = (const float*)d_in[8];
  const float* bo = (const float*)d_in[9];
  float* Out = (float*)d_out;

  char* ws = (char*)d_ws;
  bf16* Xb     = (bf16*)(ws + 0);          // 16 MB (8192x1024)
  bf16* Wqkv_t = (bf16*)(ws + 16777216);   // 6 MB  (3072x1024)
  bf16* Wot    = (bf16*)(ws + 23068672);   // 2 MB  (1024x1024)
  bf16* Qb     = (bf16*)(ws + 25165824);   // 16 MB (B,H,N,D), pre-scaled by 0.125
  bf16* Kb     = (bf16*)(ws + 41943040);   // 16 MB (B,H,N,D)
  bf16* Vt     = (bf16*)(ws + 58720256);   // 16 MB (B,H,D,N)
  bf16* AO     = Xb;                       // reuse: X consumed by gemm_qkv before attn writes

  cvt_bf16_kernel<<<8192, 256, 0, stream>>>(X, Xb);
  transpose_w_kernel<<<dim3(32, 32, 4), dim3(32, 8), 0, stream>>>(Wq, Wk, Wv, Wo, Wqkv_t, Wot);
  gemm_qkv_kernel<<<1536, 256, 0, stream>>>(Xb, Wqkv_t, bq, bk, bv, Qb, Kb, Vt);
  attn_kernel<<<2048, 256, 0, stream>>>(Qb, Kb, Vt, mask, AO);
  gemm_out_kernel<<<512, 256, 0, stream>>>(AO, Wot, bo, Out);
}

// Round 2
// 250.069 us; speedup vs baseline: 1.4374x; 1.4374x over previous
//
#include <hip/hip_runtime.h>
#include <hip/hip_bf16.h>

typedef __bf16 bf16x8 __attribute__((ext_vector_type(8)));
typedef float f32x4 __attribute__((ext_vector_type(4)));
typedef float f32x16 __attribute__((ext_vector_type(16)));
typedef int i32x2 __attribute__((ext_vector_type(2)));
typedef __hip_bfloat16 bf16;

#define NEG_INF_F (-4294967295.0f)
// fold softmax scale (1/8) and log2(e) into Q so scores are in exp2 domain
#define QK_SCALE 0.1803368801111204f

__device__ __forceinline__ f32x4 mfma_bf16(bf16x8 a, bf16x8 b, f32x4 c) {
  return __builtin_amdgcn_mfma_f32_16x16x32_bf16(a, b, c, 0, 0, 0);
}
__device__ __forceinline__ f32x16 mfma32(bf16x8 a, bf16x8 b, f32x16 c) {
  return __builtin_amdgcn_mfma_f32_32x32x16_bf16(a, b, c, 0, 0, 0);
}

__device__ __forceinline__ void gload16(const void* g, void* l) {
  __builtin_amdgcn_global_load_lds(
      (const __attribute__((address_space(1))) void*)g,
      (__attribute__((address_space(3))) void*)l, 16, 0, 0);
}

// ---------------- prep: fp32 -> bf16 convert ----------------
__global__ void cvt_bf16_kernel(const float* __restrict__ in, bf16* __restrict__ out) {
  int i = (blockIdx.x * 256 + threadIdx.x) * 4;
  float4 v = *reinterpret_cast<const float4*>(in + i);
  union { bf16 h[4]; uint2 u; } t;
  t.h[0] = __float2bfloat16(v.x);
  t.h[1] = __float2bfloat16(v.y);
  t.h[2] = __float2bfloat16(v.z);
  t.h[3] = __float2bfloat16(v.w);
  *reinterpret_cast<uint2*>(out + i) = t.u;
}

// ---------------- prep: transpose weights to (N,K) bf16 ----------------
__global__ void transpose_w_kernel(const float* __restrict__ Wq, const float* __restrict__ Wk,
                                   const float* __restrict__ Wv, const float* __restrict__ Wo,
                                   bf16* __restrict__ Wqkv_t, bf16* __restrict__ Wot) {
  __shared__ float tile[32][33];
  int z = blockIdx.z;
  const float* src = (z == 0) ? Wq : (z == 1) ? Wk : (z == 2) ? Wv : Wo;
  bf16* dst = (z < 3) ? (Wqkv_t + (size_t)z * 1048576) : Wot;
  int tx = threadIdx.x, ty = threadIdx.y;
  int c0 = blockIdx.x * 32, r0 = blockIdx.y * 32;
#pragma unroll
  for (int i = 0; i < 32; i += 8)
    tile[ty + i][tx] = src[(r0 + ty + i) * 1024 + c0 + tx];
  __syncthreads();
#pragma unroll
  for (int i = 0; i < 32; i += 8)
    dst[(c0 + ty + i) * 1024 + r0 + tx] = __float2bfloat16(tile[tx][ty + i]);
}

// ---------------- fused QKV GEMM: C = X(8192x1024) @ Wqkv^T, scatter to heads ----------------
__global__ __launch_bounds__(256) void gemm_qkv_kernel(
    const bf16* __restrict__ A, const bf16* __restrict__ Bt,
    const float* __restrict__ bq, const float* __restrict__ bk, const float* __restrict__ bv,
    bf16* __restrict__ Qb, bf16* __restrict__ Kb, bf16* __restrict__ Vt) {
  __shared__ __align__(16) bf16 As[128 * 32];
  __shared__ __align__(16) bf16 Bs[128 * 32];
  const int K = 1024;
  const int TILES_N = 24;
  int bid = blockIdx.x;
  int bm = bid / TILES_N, bn = bid % TILES_N;
  int t = threadIdx.x;
  int lane = t & 63, w = t >> 6;
  int fr = lane & 15, fk = (lane >> 4) * 8;
  int wr = w >> 1, wc = w & 1;
  int srow = t >> 2, scol = (t & 3) * 8;

  const bf16* Ablk = A + (size_t)(bm * 128) * K;
  const bf16* Bblk = Bt + (size_t)(bn * 128) * K;

  f32x4 acc[4][4] = {};

  for (int k0 = 0; k0 < K; k0 += 32) {
    gload16(Ablk + (size_t)srow * K + k0 + scol, (char*)As + t * 16);
    gload16(Ablk + (size_t)(srow + 64) * K + k0 + scol, (char*)As + 4096 + t * 16);
    gload16(Bblk + (size_t)srow * K + k0 + scol, (char*)Bs + t * 16);
    gload16(Bblk + (size_t)(srow + 64) * K + k0 + scol, (char*)Bs + 4096 + t * 16);
    __syncthreads();
    bf16x8 a[4], b[4];
#pragma unroll
    for (int m = 0; m < 4; m++) a[m] = *(const bf16x8*)&As[(wr * 64 + m * 16 + fr) * 32 + fk];
#pragma unroll
    for (int n = 0; n < 4; n++) b[n] = *(const bf16x8*)&Bs[(wc * 64 + n * 16 + fr) * 32 + fk];
#pragma unroll
    for (int m = 0; m < 4; m++)
#pragma unroll
      for (int n = 0; n < 4; n++)
        acc[m][n] = mfma_bf16(a[m], b[n], acc[m][n]);
    __syncthreads();
  }

  int sel = (bn * 128) >> 10;  // uniform per block (1024 % 128 == 0)
  const float* bias = (sel == 0) ? bq : (sel == 1) ? bk : bv;
#pragma unroll
  for (int m = 0; m < 4; m++) {
#pragma unroll
    for (int n = 0; n < 4; n++) {
      f32x4 c = acc[m][n];
#pragma unroll
      for (int j = 0; j < 4; j++) {
        int grow = bm * 128 + wr * 64 + m * 16 + (lane >> 4) * 4 + j;
        int gcol = bn * 128 + wc * 64 + n * 16 + fr;
        int cc = gcol & 1023;
        float val = c[j] + bias[cc];
        int bb = grow >> 10, nr = grow & 1023;
        int h = cc >> 6, d = cc & 63;
        int bh = bb * 16 + h;
        if (sel == 0) {
          Qb[((size_t)bh * 1024 + nr) * 64 + d] = __float2bfloat16(val * QK_SCALE);
        } else if (sel == 1) {
          Kb[((size_t)bh * 1024 + nr) * 64 + d] = __float2bfloat16(val);
        } else {
          Vt[((size_t)bh * 64 + d) * 1024 + nr] = __float2bfloat16(val);
        }
      }
    }
  }
}

// ---------------- flash attention, 32x32 swapped-operand structure ----------------
// grid 1024: logical = (bid&7)*128 + bid>>3 keeps each head's 8 q-blocks on one XCD.
// 4 independent waves/block; wave owns 32 q-rows. Per 32-key tile:
//   S^T = mfma32(K,Q) x4  -> keys lane-local (16 regs) -> in-lane softmax (exp2 domain)
//   P->bf16 pack + 4 permlane32_swap -> B-frag; O^T += mfma32(Vt, P) x4.
__global__ __launch_bounds__(256) void attn_kernel(
    const bf16* __restrict__ Qb, const bf16* __restrict__ Kb, const bf16* __restrict__ Vt,
    const int* __restrict__ mask, bf16* __restrict__ AO) {
  __shared__ unsigned long long mbits64[16];

  int bid = blockIdx.x;
  int logical = (bid & 7) * 128 + (bid >> 3);
  int bh = logical >> 3;
  int qt = logical & 7;
  int b = bh >> 4, h = bh & 15;
  int t = threadIdx.x, w = t >> 6, lane = t & 63;
  int ql = lane & 31, hi = lane >> 5, hi8 = hi * 8;

  // mask bitmap: 1024 bits in LDS
  {
    int base = b * 1024 + w * 256;
#pragma unroll
    for (int r = 0; r < 4; r++) {
      unsigned long long bal = __ballot(mask[base + r * 64 + lane] != 0);
      if (lane == 0) mbits64[w * 4 + r] = bal;
    }
  }
  __syncthreads();
  const unsigned* mbits32 = (const unsigned*)mbits64;

  const bf16* Qh = Qb + (size_t)bh * 65536;
  const bf16* Kh = Kb + (size_t)bh * 65536;
  const bf16* Vh = Vt + (size_t)bh * 65536;

  int qn = qt * 128 + w * 32;
  bf16x8 qf[4];
#pragma unroll
  for (int c = 0; c < 4; c++)
    qf[c] = *(const bf16x8*)&Qh[(qn + ql) * 64 + c * 16 + hi8];

  f32x16 accO0 = {}, accO1 = {};
  float mrow = -3.0e38f, lrow = 0.0f;

  for (int kt = 0; kt < 1024; kt += 32) {
    unsigned mb = mbits32[kt >> 5] >> (hi * 4);
    // S^T = K @ Q^T over D=64 (4 chunks of 16)
    f32x16 s = {};
#pragma unroll
    for (int c = 0; c < 4; c++) {
      bf16x8 kf = *(const bf16x8*)&Kh[(kt + ql) * 64 + c * 16 + hi8];
      s = mfma32(kf, qf[c], s);
    }
    // mask (key = kt + (r&3) + 8*(r>>2) + 4*hi)
#pragma unroll
    for (int r = 0; r < 16; r++) {
      unsigned bit = (mb >> ((r & 3) + 8 * (r >> 2))) & 1u;
      s[r] = bit ? s[r] : NEG_INF_F;
    }
    // tile row-max: in-lane over 16, then cross-half
    float pm = s[0];
#pragma unroll
    for (int r = 1; r < 16; r++) pm = fmaxf(pm, s[r]);
    pm = fmaxf(pm, __shfl_xor(pm, 32));
    // defer-max (T13): rescale only when max grew past threshold
    if (!__all(pm - mrow <= 8.0f)) {
      float mnew = fmaxf(mrow, pm);
      float corr = __builtin_amdgcn_exp2f(mrow - mnew);
      lrow *= corr;
#pragma unroll
      for (int r = 0; r < 16; r++) { accO0[r] *= corr; accO1[r] *= corr; }
      mrow = mnew;
    }
    // p = exp2(s - m), row-sum
    float ls = 0.0f;
#pragma unroll
    for (int r = 0; r < 16; r++) {
      s[r] = __builtin_amdgcn_exp2f(s[r] - mrow);
      ls += s[r];
    }
    ls += __shfl_xor(ls, 32);
    lrow += ls;
    // pack P to bf16 pairs; words i: keys (4hi + {2i,2i+1 within quad}) per derivation
    unsigned wds[8];
#pragma unroll
    for (int i = 0; i < 8; i++) {
      union { bf16 q[2]; unsigned u; } pk_;
      pk_.q[0] = __float2bfloat16(s[2 * i]);
      pk_.q[1] = __float2bfloat16(s[2 * i + 1]);
      wds[i] = pk_.u;
    }
    // redistribute halves: B-frag words for the two 16-key steps
    i32x2 r02 = __builtin_amdgcn_permlane32_swap((int)wds[0], (int)wds[2], false, false);
    i32x2 r13 = __builtin_amdgcn_permlane32_swap((int)wds[1], (int)wds[3], false, false);
    i32x2 r46 = __builtin_amdgcn_permlane32_swap((int)wds[4], (int)wds[6], false, false);
    i32x2 r57 = __builtin_amdgcn_permlane32_swap((int)wds[5], (int)wds[7], false, false);
    union { int i[4]; bf16x8 v; } y0, y1;
    y0.i[0] = r02[0]; y0.i[1] = r13[0]; y0.i[2] = r02[1]; y0.i[3] = r13[1];
    y1.i[0] = r46[0]; y1.i[1] = r57[0]; y1.i[2] = r46[1]; y1.i[3] = r57[1];
    // O^T += V^T @ P^T : A-frag = Vt rows (d), two d-tiles x two 16-key steps
    bf16x8 vf00 = *(const bf16x8*)&Vh[(size_t)ql * 1024 + kt + hi8];
    bf16x8 vf01 = *(const bf16x8*)&Vh[(size_t)ql * 1024 + kt + 16 + hi8];
    bf16x8 vf10 = *(const bf16x8*)&Vh[(size_t)(32 + ql) * 1024 + kt + hi8];
    bf16x8 vf11 = *(const bf16x8*)&Vh[(size_t)(32 + ql) * 1024 + kt + 16 + hi8];
    accO0 = mfma32(vf00, y0.v, accO0);
    accO0 = mfma32(vf01, y1.v, accO0);
    accO1 = mfma32(vf10, y0.v, accO1);
    accO1 = mfma32(vf11, y1.v, accO1);
  }

  // epilogue: O = O^T / l, write (B,N,H*D) bf16; d = dt*32 + 8q + 4hi + j
  float rl = 1.0f / lrow;
  size_t rowbase = ((size_t)(b * 1024 + qn + ql)) * 1024 + h * 64;
  auto store_tile = [&](const f32x16& a, int dt) {
#pragma unroll
    for (int q = 0; q < 4; q++) {
      union { bf16 h4[4]; uint2 u; } o;
#pragma unroll
      for (int j = 0; j < 4; j++) o.h4[j] = __float2bfloat16(a[4 * q + j] * rl);
      *(uint2*)&AO[rowbase + dt * 32 + q * 8 + 4 * hi] = o.u;
    }
  };
  store_tile(accO0, 0);
  store_tile(accO1, 1);
}

// ---------------- output projection GEMM -> fp32 out ----------------
__global__ __launch_bounds__(256) void gemm_out_kernel(
    const bf16* __restrict__ A, const bf16* __restrict__ Bt,
    const float* __restrict__ bo, float* __restrict__ Out) {
  __shared__ __align__(16) bf16 As[128 * 32];
  __shared__ __align__(16) bf16 Bs[128 * 32];
  const int K = 1024;
  const int TILES_N = 8;
  int bid = blockIdx.x;
  int bm = bid / TILES_N, bn = bid % TILES_N;
  int t = threadIdx.x;
  int lane = t & 63, w = t >> 6;
  int fr = lane & 15, fk = (lane >> 4) * 8;
  int wr = w >> 1, wc = w & 1;
  int srow = t >> 2, scol = (t & 3) * 8;

  const bf16* Ablk = A + (size_t)(bm * 128) * K;
  const bf16* Bblk = Bt + (size_t)(bn * 128) * K;

  f32x4 acc[4][4] = {};

  for (int k0 = 0; k0 < K; k0 += 32) {
    gload16(Ablk + (size_t)srow * K + k0 + scol, (char*)As + t * 16);
    gload16(Ablk + (size_t)(srow + 64) * K + k0 + scol, (char*)As + 4096 + t * 16);
    gload16(Bblk + (size_t)srow * K + k0 + scol, (char*)Bs + t * 16);
    gload16(Bblk + (size_t)(srow + 64) * K + k0 + scol, (char*)Bs + 4096 + t * 16);
    __syncthreads();
    bf16x8 a[4], b[4];
#pragma unroll
    for (int m = 0; m < 4; m++) a[m] = *(const bf16x8*)&As[(wr * 64 + m * 16 + fr) * 32 + fk];
#pragma unroll
    for (int n = 0; n < 4; n++) b[n] = *(const bf16x8*)&Bs[(wc * 64 + n * 16 + fr) * 32 + fk];
#pragma unroll
    for (int m = 0; m < 4; m++)
#pragma unroll
      for (int n = 0; n < 4; n++)
        acc[m][n] = mfma_bf16(a[m], b[n], acc[m][n]);
    __syncthreads();
  }

#pragma unroll
  for (int m = 0; m < 4; m++) {
#pragma unroll
    for (int n = 0; n < 4; n++) {
      f32x4 c = acc[m][n];
#pragma unroll
      for (int j = 0; j < 4; j++) {
        int grow = bm * 128 + wr * 64 + m * 16 + (lane >> 4) * 4 + j;
        int gcol = bn * 128 + wc * 64 + n * 16 + fr;
        Out[(size_t)grow * 1024 + gcol] = c[j] + bo[gcol];
      }
    }
  }
}

extern "C" void kernel_launch(void* const* d_in, const int* in_sizes, int n_in,
                              void* d_out, int out_size, void* d_ws, size_t ws_size,
                              hipStream_t stream) {
  const float* X = (const float*)d_in[0];
  const int* mask = (const int*)d_in[1];
  const float* Wq = (const float*)d_in[2];
  const float* bq = (const float*)d_in[3];
  const float* Wk = (const float*)d_in[4];
  const float* bk = (const float*)d_in[5];
  const float* Wv = (const float*)d_in[6];
  const float* bv = (const float*)d_in[7];
  const float* Wo = (const float*)d_in[8];
  const float* bo = (const float*)d_in[9];
  float* Out = (float*)d_out;

  char* ws = (char*)d_ws;
  bf16* Xb     = (bf16*)(ws + 0);          // 16 MB (8192x1024)
  bf16* Wqkv_t = (bf16*)(ws + 16777216);   // 6 MB  (3072x1024)
  bf16* Wot    = (bf16*)(ws + 23068672);   // 2 MB  (1024x1024)
  bf16* Qb     = (bf16*)(ws + 25165824);   // 16 MB (B,H,N,D), pre-scaled by 0.125*log2(e)
  bf16* Kb     = (bf16*)(ws + 41943040);   // 16 MB (B,H,N,D)
  bf16* Vt     = (bf16*)(ws + 58720256);   // 16 MB (B,H,D,N)
  bf16* AO     = Xb;                       // reuse: X consumed by gemm_qkv before attn writes

  cvt_bf16_kernel<<<8192, 256, 0, stream>>>(X, Xb);
  transpose_w_kernel<<<dim3(32, 32, 4), dim3(32, 8), 0, stream>>>(Wq, Wk, Wv, Wo, Wqkv_t, Wot);
  gemm_qkv_kernel<<<1536, 256, 0, stream>>>(Xb, Wqkv_t, bq, bk, bv, Qb, Kb, Vt);
  attn_kernel<<<1024, 256, 0, stream>>>(Qb, Kb, Vt, mask, AO);
  gemm_out_kernel<<<512, 256, 0, stream>>>(AO, Wot, bo, Out);
}